// Round 1
// baseline (958.553 us; speedup 1.0000x reference)
//
#include <hip/hip_runtime.h>

// PatchConv2d: out[b,o,h,w] = conv3x3(x, kernel)[b,o,h,w]
//                            + 0.1*(h+w)*patch_sum[b,h,w] + bias[o]
// x: (16,64,128,128) f32, kernel: (128,64,3,3) f32, bias: (128,) f32
// out: (16,128,128,128) f32
// grid2d[h,w] == h + w for the 128x128 square case (verified from the
// reference's meshgrid/reshape gymnastics).

#define B_COEF 0.1f

constexpr int CI = 64, CO = 128, H = 128, W = 128;
constexpr int TH = 16, TW = 64;          // output tile per block
constexpr int OCPB = 8;                  // output channels per block
constexpr int HALO_H = TH + 2;           // 18
constexpr int HALO_W = TW + 2;           // 66
constexpr int XS_STRIDE = 68;            // padded LDS row stride (floats)
constexpr int WLDS_N = OCPB * CI * 9;    // 4608 floats

__global__ __launch_bounds__(256)
void patchconv_kernel(const float* __restrict__ x,
                      const float* __restrict__ wgt,
                      const float* __restrict__ bias,
                      float* __restrict__ out) {
    __shared__ __align__(16) float w_lds[WLDS_N];          // [ci][oc_l][9]
    __shared__ __align__(16) float xs[HALO_H * XS_STRIDE]; // halo input tile

    const int tid   = threadIdx.x;
    const int tilew = blockIdx.x & 1;   // 2 w-tiles
    const int tileh = blockIdx.x >> 1;  // 8 h-tiles
    const int og    = blockIdx.y;       // 16 oc groups of 8
    const int b     = blockIdx.z;       // 16 batches
    const int h0 = tileh * TH;
    const int w0 = tilew * TW;

    // ---- stage this block's weights once: global [oc][ci][3][3] -> LDS [ci][oc_l][9]
    for (int idx = tid; idx < WLDS_N; idx += 256) {
        int oc_l = idx / 576;                 // 576 = CI*9
        int rem  = idx - oc_l * 576;
        int ci   = rem / 9;
        int k    = rem - ci * 9;
        w_lds[ci * (OCPB * 9) + oc_l * 9 + k] =
            wgt[(og * OCPB + oc_l) * 576 + rem];
    }

    const int r     = tid >> 4;   // 0..15 row within tile
    const int c16   = tid & 15;   // 0..15
    const int cbase = c16 * 4;    // 4 consecutive output cols per thread

    float acc[OCPB][4];
#pragma unroll
    for (int oc = 0; oc < OCPB; ++oc)
#pragma unroll
        for (int j = 0; j < 4; ++j) acc[oc][j] = 0.0f;
    float psum[4] = {0.f, 0.f, 0.f, 0.f};

    const float* xb = x + (size_t)b * CI * H * W;

    for (int ci = 0; ci < CI; ++ci) {
        // ---- stage 18x66 halo tile (zero-padded at image edges)
        for (int idx = tid; idx < HALO_H * HALO_W; idx += 256) {
            int rr = idx / HALO_W;
            int cc = idx - rr * HALO_W;
            int gh = h0 - 1 + rr;
            int gw = w0 - 1 + cc;
            float v = 0.0f;
            if (gh >= 0 && gh < H && gw >= 0 && gw < W)
                v = xb[(ci * H + gh) * W + gw];
            xs[rr * XS_STRIDE + cc] = v;
        }
        __syncthreads();

        // ---- weights for this ci: 72 floats, broadcast b128 reads
        float wreg[OCPB * 9];
        const float4* wv = (const float4*)(w_lds + ci * (OCPB * 9));
#pragma unroll
        for (int q = 0; q < (OCPB * 9) / 4; ++q)
            ((float4*)wreg)[q] = wv[q];

        // ---- input patch: 3 rows x 6 cols covers the 4 output pixels
        float xp[3][6];
#pragma unroll
        for (int a = 0; a < 3; ++a)
#pragma unroll
            for (int cc = 0; cc < 6; ++cc)
                xp[a][cc] = xs[(r + a) * XS_STRIDE + cbase + cc];

        // ---- patch sum (shared across all oc)
#pragma unroll
        for (int j = 0; j < 4; ++j) {
            float s = 0.0f;
#pragma unroll
            for (int a = 0; a < 3; ++a)
#pragma unroll
                for (int bb = 0; bb < 3; ++bb) s += xp[a][j + bb];
            psum[j] += s;
        }

        // ---- 8 oc x 4 px x 9 taps
#pragma unroll
        for (int oc = 0; oc < OCPB; ++oc)
#pragma unroll
            for (int a = 0; a < 3; ++a)
#pragma unroll
                for (int bb = 0; bb < 3; ++bb) {
                    float wv_s = wreg[oc * 9 + a * 3 + bb];
#pragma unroll
                    for (int j = 0; j < 4; ++j)
                        acc[oc][j] = fmaf(wv_s, xp[a][j + bb], acc[oc][j]);
                }

        __syncthreads();
    }

    // ---- epilogue: + 0.1*(h+w)*patch_sum + bias, coalesced float4 stores
    const int hh = h0 + r;
#pragma unroll
    for (int oc = 0; oc < OCPB; ++oc) {
        const int oc_g = og * OCPB + oc;
        const float bv = bias[oc_g];
        float4 v;
        v.x = fmaf(B_COEF * (float)(hh + w0 + cbase + 0), psum[0], acc[oc][0]) + bv;
        v.y = fmaf(B_COEF * (float)(hh + w0 + cbase + 1), psum[1], acc[oc][1]) + bv;
        v.z = fmaf(B_COEF * (float)(hh + w0 + cbase + 2), psum[2], acc[oc][2]) + bv;
        v.w = fmaf(B_COEF * (float)(hh + w0 + cbase + 3), psum[3], acc[oc][3]) + bv;
        *(float4*)(out + (((size_t)b * CO + oc_g) * H + hh) * W + w0 + cbase) = v;
    }
}

extern "C" void kernel_launch(void* const* d_in, const int* in_sizes, int n_in,
                              void* d_out, int out_size, void* d_ws, size_t ws_size,
                              hipStream_t stream) {
    const float* x    = (const float*)d_in[0];
    const float* wgt  = (const float*)d_in[1];
    const float* bias = (const float*)d_in[2];
    float* out = (float*)d_out;

    dim3 grid(16, CO / OCPB, 16);  // (h,w tiles) x (oc groups) x batch
    dim3 block(256);
    patchconv_kernel<<<grid, block, 0, stream>>>(x, wgt, bias, out);
}

// Round 2
// 313.405 us; speedup vs baseline: 3.0585x; 3.0585x over previous
//
#include <hip/hip_runtime.h>
#include <hip/hip_bf16.h>

// PatchConv2d: out[b,o,h,w] = conv3x3(x,kernel) + 0.1*(h+w)*patch_sum[b,h,w] + bias[o]
// x: (16,64,128,128) f32, kernel: (128,64,3,3) f32, bias: (128,) f32 -> out (16,128,128,128) f32
//
// Implicit-GEMM on MFMA: per block = one (b,h) output row, M=128 px, N=128 oc,
// K = 9 taps x 64 ci. bf16 inputs, fp32 accumulate; patch_sum kept in fp32.

typedef __attribute__((ext_vector_type(8))) short short8;
typedef __attribute__((ext_vector_type(4))) float f32x4;

#define B_COEF 0.1f
constexpr int CI = 64, CO = 128, H = 128, W = 128;
constexpr int XPAD = 72;   // LDS stride (elems) for x row tile  [130][XPAD]
constexpr int WPAD = 72;   // LDS stride (elems) for weight tile [128][WPAD]

// ---- prep: kernel fp32 [oc][ci][3][3] -> bf16 w_t[tap][oc][ci] in d_ws ----
__global__ void prep_w(const float* __restrict__ wgt, __hip_bfloat16* __restrict__ wt) {
    int idx = blockIdx.x * 256 + threadIdx.x;          // 9*128*64 = 73728
    if (idx < 9 * CO * CI) {
        int tap = idx / (CO * CI);
        int rem = idx - tap * (CO * CI);
        int oc = rem >> 6, ci = rem & 63;
        wt[idx] = __float2bfloat16(wgt[(oc * CI + ci) * 9 + tap]);
    }
}

__global__ __launch_bounds__(256, 2)
void conv_main(const float* __restrict__ x, const __hip_bfloat16* __restrict__ wt,
               const float* __restrict__ bias, float* __restrict__ out) {
    __shared__ __hip_bfloat16 xrow[130 * XPAD];   // [w 0..129][ci], bf16
    __shared__ __hip_bfloat16 wlds[CO * WPAD];    // [oc][ci] for current tap
    __shared__ float colsum[132];                 // fp32 per-column (w) channel+row sums

    const int tid    = threadIdx.x;
    const int h      = blockIdx.x;
    const int b      = blockIdx.y;
    const int lane   = tid & 63;
    const int waveid = tid >> 6;
    const int lo16   = lane & 15;
    const int quad   = lane >> 4;
    const int m0     = (waveid & 1) * 64;   // wave's pixel offset
    const int n0     = (waveid >> 1) * 64;  // wave's oc offset

    f32x4 acc[4][4] = {};

    if (tid < 132) colsum[tid] = 0.0f;

    const float* xb = x + (size_t)b * CI * H * W;

    // staging lane constants: lane = (cipl:2)(w16:4); rest = wave + 4*it
    const int w16   = tid & 15;
    const int cipl  = (tid >> 4) & 3;
    const int rest0 = tid >> 6;

    for (int kh = 0; kh < 3; ++kh) {
        const int gh = h - 1 + kh;
        __syncthreads();  // previous tap's xrow/wlds readers done
        // ---- stage x row (transpose ci<->w, fp32->bf16), accumulate colsum fp32
        for (int it = 0; it < 18; ++it) {
            int rest = rest0 + it * 4;        // 0..71
            int whi  = rest % 9;
            int ciph = rest / 9;
            int w    = whi * 16 + w16;        // 0..143 (valid < 130)
            int ci0  = (ciph * 4 + cipl) * 2; // 0..62 even
            int gw   = w - 1;
            float x0 = 0.0f, x1 = 0.0f;
            if (w < 130 && gw >= 0 && gw < W && gh >= 0 && gh < H) {
                const float* p = xb + (size_t)ci0 * (H * W) + gh * W + gw;
                x0 = p[0];
                x1 = p[H * W];
            }
            if (w < 130) {
                __hip_bfloat162 pk;
                pk.x = __float2bfloat16(x0);
                pk.y = __float2bfloat16(x1);
                *(__hip_bfloat162*)&xrow[w * XPAD + ci0] = pk;
            }
            float cs = x0 + x1;
            cs += __shfl_xor(cs, 16);
            cs += __shfl_xor(cs, 32);
            if (quad == 0 && w < 130) atomicAdd(&colsum[w], cs);
        }

        for (int kw = 0; kw < 3; ++kw) {
            __syncthreads();  // xrow ready / previous wlds readers done
            // ---- stage weight slice for tap (kh,kw): w_t[tap][oc][ci] -> wlds
            {
                const __hip_bfloat16* wtap = wt + (kh * 3 + kw) * (CO * CI);
#pragma unroll
                for (int it = 0; it < 4; ++it) {
                    int j  = tid + it * 256;
                    int oc = j >> 3;
                    int c8 = (j & 7) * 8;
                    short8 v = *(const short8*)(wtap + oc * CI + c8);
                    *(short8*)&wlds[oc * WPAD + c8] = v;
                }
            }
            __syncthreads();  // wlds ready

            // ---- 2 k-chunks of 32 ci
#pragma unroll
            for (int kc = 0; kc < 2; ++kc) {
                const int krow = kc * 32 + quad * 8;
                short8 af[4], bf[4];
#pragma unroll
                for (int mi = 0; mi < 4; ++mi)
                    af[mi] = *(const short8*)&xrow[(m0 + mi * 16 + lo16 + kw) * XPAD + krow];
#pragma unroll
                for (int ni = 0; ni < 4; ++ni)
                    bf[ni] = *(const short8*)&wlds[(n0 + ni * 16 + lo16) * WPAD + krow];
#pragma unroll
                for (int mi = 0; mi < 4; ++mi)
#pragma unroll
                    for (int ni = 0; ni < 4; ++ni)
                        acc[mi][ni] = __builtin_amdgcn_mfma_f32_16x16x32_bf16(
                            af[mi], bf[ni], acc[mi][ni], 0, 0, 0);
            }
        }
    }

    __syncthreads();  // colsum complete

    // ---- epilogue: + 0.1*(h+w)*patch_sum + bias; float4 stores
#pragma unroll
    for (int mi = 0; mi < 4; ++mi) {
        const int wbase = m0 + mi * 16 + quad * 4;
        float cs[6];
#pragma unroll
        for (int r = 0; r < 6; ++r) cs[r] = colsum[wbase + r];
        float ps[4], cf[4];
#pragma unroll
        for (int r = 0; r < 4; ++r) {
            ps[r] = cs[r] + cs[r + 1] + cs[r + 2];
            cf[r] = B_COEF * (float)(h + wbase + r);
        }
#pragma unroll
        for (int ni = 0; ni < 4; ++ni) {
            const int oc = n0 + ni * 16 + lo16;
            const float bv = bias[oc];
            f32x4 v = acc[mi][ni];
#pragma unroll
            for (int r = 0; r < 4; ++r) v[r] = v[r] + cf[r] * ps[r] + bv;
            *(f32x4*)(out + (((size_t)b * CO + oc) * H + h) * W + wbase) = v;
        }
    }
}

extern "C" void kernel_launch(void* const* d_in, const int* in_sizes, int n_in,
                              void* d_out, int out_size, void* d_ws, size_t ws_size,
                              hipStream_t stream) {
    const float* x    = (const float*)d_in[0];
    const float* wgt  = (const float*)d_in[1];
    const float* bias = (const float*)d_in[2];
    float* out = (float*)d_out;
    __hip_bfloat16* wt = (__hip_bfloat16*)d_ws;   // 9*128*64*2 = 147,456 B

    prep_w<<<dim3(288), dim3(256), 0, stream>>>(wgt, wt);
    conv_main<<<dim3(H, 16), dim3(256), 0, stream>>>(x, wt, bias, out);
}

// Round 3
// 249.059 us; speedup vs baseline: 3.8487x; 1.2584x over previous
//
#include <hip/hip_runtime.h>
#include <hip/hip_bf16.h>

// PatchConv2d: out[b,o,h,w] = conv3x3(x,kernel) + 0.1*(h+w)*patch_sum[b,h,w] + bias[o]
// x:(16,64,128,128) f32, kernel:(128,64,3,3) f32, bias:(128,) f32 -> out(16,128,128,128) f32
//
// R3: NHWC bf16 pre-transpose + channel-sum image S, weights in per-tap
// [tap][kc][oc][32ci] layout (B-frags loaded straight from L2, no LDS/barrier).
// Main kernel: stage 3 halo rows once, ONE barrier, then 9 unrolled taps of
// pure ds_read_b128 + global short8 + MFMA.

typedef __attribute__((ext_vector_type(8))) short short8;
typedef __attribute__((ext_vector_type(4))) float f32x4;

#define B_COEF 0.1f
constexpr int CI = 64, CO = 128, H = 128, W = 128;
constexpr int XPAD = 72;  // LDS row stride (elems): 36 dwords -> conflict-free b128

static __device__ inline short bf16s(float v) {
    __hip_bfloat16 b = __float2bfloat16(v);
    return *reinterpret_cast<short*>(&b);
}

// ============================ fast path ====================================

// x NCHW f32 -> x_t NHWC bf16 ; S[b][h][w] = sum_ci x (fp32)
__global__ __launch_bounds__(256)
void prep_x(const float* __restrict__ x, __hip_bfloat16* __restrict__ xt,
            float* __restrict__ S) {
    __shared__ float tile[64 * 129];
    __shared__ float ssum[256];
    const int h = blockIdx.x, b = blockIdx.y, tid = threadIdx.x;
    const int w = tid & 127, cip = tid >> 7;

    float sacc = 0.0f;
    for (int it = 0; it < 32; ++it) {
        int ci = it * 2 + cip;
        float v = x[(((size_t)b * CI + ci) * H + h) * W + w];
        tile[ci * 129 + w] = v;
        sacc += v;
    }
    ssum[tid] = sacc;
    __syncthreads();
    if (tid < 128)
        S[((size_t)b * H + h) * W + tid] = ssum[tid] + ssum[tid + 128];

    const int c8 = (tid & 7) * 8, wl = tid >> 3;
#pragma unroll
    for (int it = 0; it < 4; ++it) {
        int ww = wl + it * 32;
        short8 pk;
#pragma unroll
        for (int j = 0; j < 8; ++j)
            pk[j] = bf16s(tile[(c8 + j) * 129 + ww]);
        *(short8*)(xt + (((size_t)b * H + h) * W + ww) * CI + c8) = pk;
    }
}

// kernel f32 [oc][ci][3][3] -> bf16 wq[tap][kc][oc][32] (ci = kc*32+j)
__global__ void prep_wq(const float* __restrict__ wgt, __hip_bfloat16* __restrict__ wq) {
    int idx = blockIdx.x * 256 + threadIdx.x;  // 9*128*64 = 73728
    if (idx < 9 * CO * CI) {
        int tap = idx >> 13;
        int rem = idx & 8191;
        int oc = rem >> 6, ci = rem & 63;
        int kc = ci >> 5, j = ci & 31;
        wq[(((tap * 2 + kc) * CO + oc) << 5) + j] =
            __float2bfloat16(wgt[(oc * CI + ci) * 9 + tap]);
    }
}

__global__ __launch_bounds__(256, 2)
void conv_main(const __hip_bfloat16* __restrict__ xt,
               const __hip_bfloat16* __restrict__ wq,
               const float* __restrict__ S,
               const float* __restrict__ bias,
               float* __restrict__ out) {
    __shared__ __hip_bfloat16 xrow[3][130 * XPAD];
    __shared__ float ssum[132];

    const int tid = threadIdx.x, h = blockIdx.x, b = blockIdx.y;
    const int lane = tid & 63, waveid = tid >> 6;
    const int lo16 = lane & 15, quad = lane >> 4;
    const int m0 = (waveid & 1) * 64, n0 = (waveid >> 1) * 64;

    // ---- stage 3 halo rows (vector dwordx4, zero-padded edges)
    const int c8 = (tid & 7) * 8, wl = tid >> 3;
#pragma unroll
    for (int r = 0; r < 3; ++r) {
        const int gh = h - 1 + r;
#pragma unroll
        for (int it = 0; it < 5; ++it) {
            int w = wl + it * 32;
            if (w < 130) {
                int gw = w - 1;
                short8 v = {0, 0, 0, 0, 0, 0, 0, 0};
                if (gh >= 0 && gh < H && gw >= 0 && gw < W)
                    v = *(const short8*)(xt + (((size_t)b * H + gh) * W + gw) * CI + c8);
                *(short8*)&xrow[r][w * XPAD + c8] = v;
            }
        }
    }
    // ---- stage kh-summed S window (patch_sum precursor)
    if (tid < 130) {
        int gw = tid - 1;
        float s = 0.0f;
        if (gw >= 0 && gw < W) {
#pragma unroll
            for (int r = 0; r < 3; ++r) {
                int gh = h - 1 + r;
                if (gh >= 0 && gh < H) s += S[((size_t)b * H + gh) * W + gw];
            }
        }
        ssum[tid] = s;
    }
    __syncthreads();  // the only barrier

    f32x4 acc[4][4] = {};

#pragma unroll
    for (int kh = 0; kh < 3; ++kh) {
#pragma unroll
        for (int kw = 0; kw < 3; ++kw) {
            const int tap = kh * 3 + kw;
            // B-frags straight from L2-resident wq (1 KB coalesced per load)
            short8 bq[2][4];
#pragma unroll
            for (int kc = 0; kc < 2; ++kc)
#pragma unroll
                for (int ni = 0; ni < 4; ++ni)
                    bq[kc][ni] = *(const short8*)(
                        wq + (((tap * 2 + kc) * CO + n0 + ni * 16 + lo16) << 5) + quad * 8);
#pragma unroll
            for (int kc = 0; kc < 2; ++kc) {
                short8 af[4];
#pragma unroll
                for (int mi = 0; mi < 4; ++mi)
                    af[mi] = *(const short8*)
                        &xrow[kh][(m0 + mi * 16 + lo16 + kw) * XPAD + kc * 32 + quad * 8];
#pragma unroll
                for (int mi = 0; mi < 4; ++mi)
#pragma unroll
                    for (int ni = 0; ni < 4; ++ni)
                        acc[mi][ni] = __builtin_amdgcn_mfma_f32_16x16x32_bf16(
                            af[mi], bq[kc][ni], acc[mi][ni], 0, 0, 0);
            }
        }
    }

    // ---- epilogue: + 0.1*(h+w)*patch_sum + bias; float4 stores
#pragma unroll
    for (int mi = 0; mi < 4; ++mi) {
        const int wbase = m0 + mi * 16 + quad * 4;
        float cs[6];
#pragma unroll
        for (int r = 0; r < 6; ++r) cs[r] = ssum[wbase + r];
        float ps[4], cf[4];
#pragma unroll
        for (int r = 0; r < 4; ++r) {
            ps[r] = cs[r] + cs[r + 1] + cs[r + 2];
            cf[r] = B_COEF * (float)(h + wbase + r);
        }
#pragma unroll
        for (int ni = 0; ni < 4; ++ni) {
            const int oc = n0 + ni * 16 + lo16;
            const float bv = bias[oc];
            f32x4 v = acc[mi][ni];
#pragma unroll
            for (int r = 0; r < 4; ++r) v[r] = v[r] + cf[r] * ps[r] + bv;
            *(f32x4*)(out + (((size_t)b * CO + oc) * H + h) * W + wbase) = v;
        }
    }
}

// ===================== fallback path (R2, needs only 147 KB ws) ============

constexpr int WPAD = 72;

__global__ void prep_w_fb(const float* __restrict__ wgt, __hip_bfloat16* __restrict__ wt) {
    int idx = blockIdx.x * 256 + threadIdx.x;
    if (idx < 9 * CO * CI) {
        int tap = idx / (CO * CI);
        int rem = idx - tap * (CO * CI);
        int oc = rem >> 6, ci = rem & 63;
        wt[idx] = __float2bfloat16(wgt[(oc * CI + ci) * 9 + tap]);
    }
}

__global__ __launch_bounds__(256, 2)
void conv_fb(const float* __restrict__ x, const __hip_bfloat16* __restrict__ wt,
             const float* __restrict__ bias, float* __restrict__ out) {
    __shared__ __hip_bfloat16 xrow[130 * XPAD];
    __shared__ __hip_bfloat16 wlds[CO * WPAD];
    __shared__ float colsum[132];

    const int tid = threadIdx.x;
    const int h = blockIdx.x, b = blockIdx.y;
    const int lane = tid & 63, waveid = tid >> 6;
    const int lo16 = lane & 15, quad = lane >> 4;
    const int m0 = (waveid & 1) * 64, n0 = (waveid >> 1) * 64;

    f32x4 acc[4][4] = {};
    if (tid < 132) colsum[tid] = 0.0f;
    const float* xb = x + (size_t)b * CI * H * W;

    const int w16 = tid & 15, cipl = (tid >> 4) & 3, rest0 = tid >> 6;

    for (int kh = 0; kh < 3; ++kh) {
        const int gh = h - 1 + kh;
        __syncthreads();
        for (int it = 0; it < 18; ++it) {
            int rest = rest0 + it * 4;
            int whi = rest % 9, ciph = rest / 9;
            int w = whi * 16 + w16;
            int ci0 = (ciph * 4 + cipl) * 2;
            int gw = w - 1;
            float x0 = 0.0f, x1 = 0.0f;
            if (w < 130 && gw >= 0 && gw < W && gh >= 0 && gh < H) {
                const float* p = xb + (size_t)ci0 * (H * W) + gh * W + gw;
                x0 = p[0];
                x1 = p[H * W];
            }
            if (w < 130) {
                __hip_bfloat162 pk;
                pk.x = __float2bfloat16(x0);
                pk.y = __float2bfloat16(x1);
                *(__hip_bfloat162*)&xrow[w * XPAD + ci0] = pk;
            }
            float cs = x0 + x1;
            cs += __shfl_xor(cs, 16);
            cs += __shfl_xor(cs, 32);
            if (quad == 0 && w < 130) atomicAdd(&colsum[w], cs);
        }
        for (int kw = 0; kw < 3; ++kw) {
            __syncthreads();
            {
                const __hip_bfloat16* wtap = wt + (kh * 3 + kw) * (CO * CI);
#pragma unroll
                for (int it = 0; it < 4; ++it) {
                    int j = tid + it * 256;
                    int oc = j >> 3, ch = (j & 7) * 8;
                    short8 v = *(const short8*)(wtap + oc * CI + ch);
                    *(short8*)&wlds[oc * WPAD + ch] = v;
                }
            }
            __syncthreads();
#pragma unroll
            for (int kc = 0; kc < 2; ++kc) {
                const int krow = kc * 32 + quad * 8;
                short8 af[4], bf[4];
#pragma unroll
                for (int mi = 0; mi < 4; ++mi)
                    af[mi] = *(const short8*)&xrow[(m0 + mi * 16 + lo16 + kw) * XPAD + krow];
#pragma unroll
                for (int ni = 0; ni < 4; ++ni)
                    bf[ni] = *(const short8*)&wlds[(n0 + ni * 16 + lo16) * WPAD + krow];
#pragma unroll
                for (int mi = 0; mi < 4; ++mi)
#pragma unroll
                    for (int ni = 0; ni < 4; ++ni)
                        acc[mi][ni] = __builtin_amdgcn_mfma_f32_16x16x32_bf16(
                            af[mi], bf[ni], acc[mi][ni], 0, 0, 0);
            }
        }
    }
    __syncthreads();
#pragma unroll
    for (int mi = 0; mi < 4; ++mi) {
        const int wbase = m0 + mi * 16 + quad * 4;
        float cs[6];
#pragma unroll
        for (int r = 0; r < 6; ++r) cs[r] = colsum[wbase + r];
        float ps[4], cf[4];
#pragma unroll
        for (int r = 0; r < 4; ++r) {
            ps[r] = cs[r] + cs[r + 1] + cs[r + 2];
            cf[r] = B_COEF * (float)(h + wbase + r);
        }
#pragma unroll
        for (int ni = 0; ni < 4; ++ni) {
            const int oc = n0 + ni * 16 + lo16;
            const float bv = bias[oc];
            f32x4 v = acc[mi][ni];
#pragma unroll
            for (int r = 0; r < 4; ++r) v[r] = v[r] + cf[r] * ps[r] + bv;
            *(f32x4*)(out + (((size_t)b * CO + oc) * H + h) * W + wbase) = v;
        }
    }
}

// ===========================================================================

extern "C" void kernel_launch(void* const* d_in, const int* in_sizes, int n_in,
                              void* d_out, int out_size, void* d_ws, size_t ws_size,
                              hipStream_t stream) {
    const float* x    = (const float*)d_in[0];
    const float* wgt  = (const float*)d_in[1];
    const float* bias = (const float*)d_in[2];
    float* out = (float*)d_out;

    const size_t XT_BYTES = (size_t)16 * H * W * CI * 2;          // 33,554,432
    const size_t S_BYTES  = (size_t)16 * H * W * 4;               //  1,048,576
    const size_t WQ_BYTES = (size_t)9 * 2 * CO * 32 * 2;          //    147,456

    if (ws_size >= XT_BYTES + S_BYTES + WQ_BYTES) {
        __hip_bfloat16* xt = (__hip_bfloat16*)d_ws;
        float* S           = (float*)((char*)d_ws + XT_BYTES);
        __hip_bfloat16* wq = (__hip_bfloat16*)((char*)d_ws + XT_BYTES + S_BYTES);
        prep_x<<<dim3(H, 16), dim3(256), 0, stream>>>(x, xt, S);
        prep_wq<<<dim3(288), dim3(256), 0, stream>>>(wgt, wq);
        conv_main<<<dim3(H, 16), dim3(256), 0, stream>>>(xt, wq, S, bias, out);
    } else {
        __hip_bfloat16* wt = (__hip_bfloat16*)d_ws;  // 147,456 B
        prep_w_fb<<<dim3(288), dim3(256), 0, stream>>>(wgt, wt);
        conv_fb<<<dim3(H, 16), dim3(256), 0, stream>>>(x, wt, bias, out);
    }
}